// Round 8
// baseline (437.713 us; speedup 1.0000x reference)
//
#include <hip/hip_runtime.h>
#include <math.h>

namespace {

constexpr int N = 4, C = 96, H = 256, W = 256;
constexpr int HW = H * W;
constexpr float LMAX = 2.5f;

typedef float v4 __attribute__((ext_vector_type(4)));
struct __attribute__((packed, aligned(4))) V4U { v4 v; };
__device__ inline v4 load4u(const float* p) {
  return reinterpret_cast<const V4U*>(p)->v;
}
__device__ inline int refl(int i, int S) {
  i = i < 0 ? -i : i;
  return i >= S ? 2 * S - 2 - i : i;
}

// ------------------------------------------------------------ downsample1 ---
__global__ __launch_bounds__(256) void downsample1(
    const float* __restrict__ in, float* __restrict__ out) {
  __shared__ float s[68 * 68];
  const int Wi = 256, Wo = 128, T = 4;
  int tile = blockIdx.x, nc = blockIdx.y;
  int tx0 = (tile % T) * 32, ty0 = (tile / T) * 32;
  int ix0 = 2 * tx0 - 2, iy0 = 2 * ty0 - 2;
  const float* p = in + (size_t)nc * Wi * Wi;
  int tid = threadIdx.x;

  for (int k = 0; k < 5; k++) {
    int ch = tid + 256 * k;
    if (ch < 68 * 17) {
      int yy = ch / 17, cx = (ch - 17 * yy) * 4;
      int gy = refl(iy0 + yy, Wi);
      int gx = ix0 + cx;
      const float* rowp = p + (size_t)gy * Wi;
      float* sp = s + yy * 68 + cx;
      if (gx >= 0 && gx + 3 < Wi) {
        v4 t = load4u(rowp + gx);
        sp[0] = t.x; sp[1] = t.y; sp[2] = t.z; sp[3] = t.w;
      } else {
#pragma unroll
        for (int j = 0; j < 4; j++) sp[j] = rowp[refl(gx + j, Wi)];
      }
    }
  }
  __syncthreads();

  const float fw[4] = {0.125f, 0.375f, 0.375f, 0.125f};
  int dx = tid & 31, dy0 = tid >> 5;
  float* po = out + (size_t)nc * Wo * Wo;
#pragma unroll
  for (int r = 0; r < 4; r++) {
    int dy = dy0 + 8 * r;
    float acc = 0.0f;
#pragma unroll
    for (int a = 0; a < 4; a++) {
      const float* row = s + (2 * dy + 1 + a) * 68 + 2 * dx + 1;
      acc = fmaf(fw[a],
                 fmaf(fw[0], row[0],
                 fmaf(fw[1], row[1],
                 fmaf(fw[2], row[2], fw[3] * row[3]))), acc);
    }
    po[(size_t)(ty0 + dy) * Wo + tx0 + dx] = acc;
  }
}

// ----------------------------------------------------------- downsample23 ---
__global__ __launch_bounds__(256) void downsample23(
    const float* __restrict__ pyr1, float* __restrict__ pyr2,
    float* __restrict__ pyr3) {
  __shared__ float s1[70 * 72];
  __shared__ float h2[70 * 36];
  __shared__ float p2[34 * 36];
  __shared__ float h3[34 * 16];
  int t = blockIdx.x, nc = blockIdx.y;
  int t3x = (t & 1) * 16, t3y = (t >> 1) * 16;
  int u0x = 2 * t3x - 1, u0y = 2 * t3y - 1;
  int v0x = 2 * u0x - 1, v0y = 2 * u0y - 1;
  const float* p1 = pyr1 + (size_t)nc * 128 * 128;
  int tid = threadIdx.x;
  const float fw[4] = {0.125f, 0.375f, 0.375f, 0.125f};

  for (int k = 0; k < 20; k++) {
    int e = tid + 256 * k;
    if (e < 4900) {
      int yy = e / 70, xx = e - 70 * yy;
      s1[yy * 72 + xx] =
          p1[(size_t)refl(v0y + yy, 128) * 128 + refl(v0x + xx, 128)];
    }
  }
  __syncthreads();

  for (int k = 0; k < 10; k++) {
    int e = tid + 256 * k;
    if (e < 70 * 34) {
      int r = e / 34, c = e - 34 * r;
      const float* sp = s1 + r * 72 + 2 * c;
      h2[r * 36 + c] = fmaf(fw[0], sp[0],
                       fmaf(fw[1], sp[1],
                       fmaf(fw[2], sp[2], fw[3] * sp[3])));
    }
  }
  __syncthreads();

  for (int k = 0; k < 5; k++) {
    int e = tid + 256 * k;
    if (e < 34 * 34) {
      int r = e / 34, c = e - 34 * r;
      const float* hp = h2 + (2 * r) * 36 + c;
      p2[r * 36 + c] = fmaf(fw[0], hp[0],
                       fmaf(fw[1], hp[36],
                       fmaf(fw[2], hp[72], fw[3] * hp[108])));
    }
  }
  __syncthreads();

  float* o2 = pyr2 + (size_t)nc * 64 * 64;
#pragma unroll
  for (int k = 0; k < 4; k++) {
    int e = tid + 256 * k;
    int yy = e >> 5, xx = e & 31;
    o2[(size_t)(2 * t3y + yy) * 64 + 2 * t3x + xx] = p2[(yy + 1) * 36 + xx + 1];
  }

  for (int k = 0; k < 3; k++) {
    int e = tid + 256 * k;
    if (e < 34 * 16) {
      int r = e >> 4, c = e & 15;
      float acc = 0.f;
#pragma unroll
      for (int kk = 0; kk < 4; kk++) {
        int j = refl(2 * (t3x + c) - 1 + kk, 64) - u0x;
        acc = fmaf(fw[kk], p2[r * 36 + j], acc);
      }
      h3[r * 16 + c] = acc;
    }
  }
  __syncthreads();

  {
    int yy = tid >> 4, xx = tid & 15;
    float acc = 0.f;
#pragma unroll
    for (int kk = 0; kk < 4; kk++) {
      int j = refl(2 * (t3y + yy) - 1 + kk, 64) - u0y;
      acc = fmaf(fw[kk], h3[j * 16 + xx], acc);
    }
    pyr3[(size_t)nc * 32 * 32 + (t3y + yy) * 32 + t3x + xx] = acc;
  }
}

// ---------------------------------------------------------------- gather ----
__device__ inline void axis3(int q0, int q1, float wq, int l, int S,
                             int* ii, float* ww) {
  float inv = 1.0f / (float)(1 << l);
  float pos0 = ((float)q0 + 0.5f) * inv - 0.5f;
  float pos1 = ((float)q1 + 0.5f) * inv - 0.5f;
  int p0 = (int)floorf(pos0), p1 = (int)floorf(pos1);
  float f0 = pos0 - (float)p0, f1 = pos1 - (float)p1;
  int a0 = min(max(p0, 0), S - 1), a1 = min(max(p0 + 1, 0), S - 1);
  int b0 = min(max(p1, 0), S - 1), b1 = min(max(p1 + 1, 0), S - 1);
  int base = min(a0, b0);
  float w0 = 0.f, w1 = 0.f, w2 = 0.f;
  float v; int s;
  v = (1.0f - wq) * (1.0f - f0); s = a0 - base;
  w0 += (s == 0) ? v : 0.f; w1 += (s == 1) ? v : 0.f; w2 += (s == 2) ? v : 0.f;
  v = (1.0f - wq) * f0;          s = a1 - base;
  w0 += (s == 0) ? v : 0.f; w1 += (s == 1) ? v : 0.f; w2 += (s == 2) ? v : 0.f;
  v = wq * (1.0f - f1);          s = b0 - base;
  w0 += (s == 0) ? v : 0.f; w1 += (s == 1) ? v : 0.f; w2 += (s == 2) ? v : 0.f;
  v = wq * f1;                   s = b1 - base;
  w0 += (s == 0) ? v : 0.f; w1 += (s == 1) ? v : 0.f; w2 += (s == 2) ? v : 0.f;
  ii[0] = base;
  ii[1] = min(base + 1, S - 1);
  ii[2] = min(base + 2, S - 1);
  ww[0] = w0; ww[1] = w1; ww[2] = w2;
}

// LDS quad-planar (c = 4q+j): L2 @0: q*400 + tf*4 + j ; L3 @3200: q*144 + tf*4 + j
constexpr int L3OFF = 3200, LDSTOT = 4352;   // floats; 17 KB

__global__ __launch_bounds__(256, 6) void gather_tiled(
    const float* __restrict__ inputs, const float* __restrict__ grid,
    const float* __restrict__ pyr1, const float* __restrict__ pyr2,
    const float* __restrict__ pyr3, float* __restrict__ out) {
  __shared__ __align__(16) float lds[LDSTOT];
  int tile = blockIdx.x, g = blockIdx.y, n = blockIdx.z;
  int tx0 = (tile & 15) << 4, ty0 = (tile >> 4) << 4;
  int gb = g * 32;
  int tid = threadIdx.x;

  int px = tid & 15, py = tid >> 4;
  int x = tx0 + px, y = ty0 + py;

  // early grid loads (overlap with staging)
  const float2* gp = reinterpret_cast<const float2*>(grid) + (size_t)n * HW;
  float2 gc = gp[y * W + x];
  float2 gl = gp[y * W + max(x - 1, 0)];
  float2 gr = gp[y * W + min(x + 1, W - 1)];
  float2 gu = gp[max(y - 1, 0) * W + x];
  float2 gd = gp[min(y + 1, H - 1) * W + x];

  // staged-region origins (bounds proven in R5; unchanged)
  int rsx2 = min(max((tx0 >> 2) - 3, 0), 64 - 10);
  int rsy2 = min(max((ty0 >> 2) - 3, 0), 64 - 10);
  int rsx3 = min(max((tx0 >> 3) - 2, 0), 32 - 6);
  int rsy3 = min(max((ty0 >> 3) - 2, 0), 32 - 6);

  // ---- stage L2: 32ch x 100 taps ----
  {
    const float* base = pyr2 + ((size_t)(n * C + gb)) * (64 * 64);
    for (int k = 0; k < 13; k++) {
      int e = tid + 256 * k;
      if (e < 3200) {
        int c = e / 100, tf = e - 100 * c;
        int yy = tf / 10, xx = tf - 10 * yy;
        float t = base[(size_t)c * (64 * 64) + (rsy2 + yy) * 64 + rsx2 + xx];
        lds[(c >> 2) * 400 + tf * 4 + (c & 3)] = t;
      }
    }
  }
  // ---- stage L3: 32ch x 36 taps ----
  {
    const float* base = pyr3 + ((size_t)(n * C + gb)) * (32 * 32);
    for (int k = 0; k < 5; k++) {
      int e = tid + 256 * k;
      if (e < 1152) {
        int c = e / 36, tf = e - 36 * c;
        int yy = tf / 6, xx = tf - 6 * yy;
        float t = base[(size_t)c * (32 * 32) + (rsy3 + yy) * 32 + rsx3 + xx];
        lds[L3OFF + (c >> 2) * 144 + tf * 4 + (c & 3)] = t;
      }
    }
  }
  __syncthreads();

  // ---- inline levels ----
  float lv;
  {
    float cx = 255.0f * (gc.x + 1.0f) * 0.5f;
    float cy = 255.0f * (gc.y + 1.0f) * 0.5f;
    float m = 1.0f;
    float2 nb[4] = {gl, gr, gu, gd};
#pragma unroll
    for (int i = 0; i < 4; i++) {
      float ox = 255.0f * (nb[i].x + 1.0f) * 0.5f - cx;
      float oy = 255.0f * (nb[i].y + 1.0f) * 0.5f - cy;
      m = fmaxf(m, ox * ox + oy * oy);
    }
    lv = fminf(fmaxf(0.5f * __log2f(m), 0.0f), LMAX);
  }

  // sampling coords
  float ix = fminf(fmaxf(fmaf(gc.x + 1.0f, 128.0f, -0.5f), 0.0f), 255.0f);
  float iy = fminf(fmaxf(fmaf(gc.y + 1.0f, 128.0f, -0.5f), 0.0f), 255.0f);
  int x0 = (int)floorf(ix); float wx = ix - (float)x0; int x1 = min(x0 + 1, 255);
  int y0 = (int)floorf(iy); float wy = iy - (float)y0; int y1 = min(y0 + 1, 255);

  float lf = floorf(lv);
  int l0 = (int)lf;
  float wl = lv - lf;
  float wlA = 1.0f - wl;
  int lB = l0 + 1;

  float* po = out + ((size_t)(n * C + gb)) * HW + (size_t)y * W + x;

  if (l0 == 2) {
    // ---- common path: A = level2 (LDS), B = level3 (LDS) ----
    int xiA[3]; float xwA[3]; axis3(x0, x1, wx, 2, 64, xiA, xwA);
    int yiA[3]; float ywA[3]; axis3(y0, y1, wy, 2, 64, yiA, ywA);
    int xiB[3]; float xwB[3]; axis3(x0, x1, wx, 3, 32, xiB, xwB);
    int yiB[3]; float ywB[3]; axis3(y0, y1, wy, 3, 32, yiB, ywB);
    int tfA[9]; float wA[9];
    int tfB[9]; float wB[9];
#pragma unroll
    for (int r = 0; r < 3; r++)
#pragma unroll
      for (int cc = 0; cc < 3; cc++) {
        tfA[r * 3 + cc] = (yiA[r] - rsy2) * 10 + (xiA[cc] - rsx2);
        wA[r * 3 + cc] = ywA[r] * xwA[cc] * wlA;
        tfB[r * 3 + cc] = (yiB[r] - rsy3) * 6 + (xiB[cc] - rsx3);
        wB[r * 3 + cc] = ywB[r] * xwB[cc] * wl;
      }
#pragma unroll
    for (int q = 0; q < 8; q++) {
      const float* pA = lds + q * 400;
      const float* pB = lds + L3OFF + q * 144;
      v4 acc = {0.f, 0.f, 0.f, 0.f};
#pragma unroll
      for (int t = 0; t < 9; t++)
        acc += *reinterpret_cast<const v4*>(pA + tfA[t] * 4) * wA[t];
#pragma unroll
      for (int t = 0; t < 9; t++)
        acc += *reinterpret_cast<const v4*>(pB + tfB[t] * 4) * wB[t];
      float* pq = po + (size_t)(4 * q) * HW;
      pq[0] = acc.x; pq[HW] = acc.y;
      pq[2 * (size_t)HW] = acc.z; pq[3 * (size_t)HW] = acc.w;
    }
  } else {
    // ---- rare path: l0 in {0,1} ----
    // A: l0==0 -> bilinear(inputs, global); l0==1 -> 9-tap pyr1 (global)
    // B: lB==1 -> 9-tap pyr1 (global);      lB==2 -> LDS L2
    int goA[9]; float wAg[9];         // global pyr1 A-taps (l0==1)
    if (l0 == 1) {
      int xi[3]; float xw[3]; axis3(x0, x1, wx, 1, 128, xi, xw);
      int yi[3]; float yw[3]; axis3(y0, y1, wy, 1, 128, yi, yw);
#pragma unroll
      for (int r = 0; r < 3; r++)
#pragma unroll
        for (int cc = 0; cc < 3; cc++) {
          goA[r * 3 + cc] = yi[r] * 128 + xi[cc];
          wAg[r * 3 + cc] = yw[r] * xw[cc];
        }
    }
    int tfB[9]; float wB[9];          // LDS L2 B-taps (lB==2)
    int goB[9];                       // global pyr1 B-taps (lB==1)
    if (lB == 2) {
      int xi[3]; float xw[3]; axis3(x0, x1, wx, 2, 64, xi, xw);
      int yi[3]; float yw[3]; axis3(y0, y1, wy, 2, 64, yi, yw);
#pragma unroll
      for (int r = 0; r < 3; r++)
#pragma unroll
        for (int cc = 0; cc < 3; cc++) {
          tfB[r * 3 + cc] = (yi[r] - rsy2) * 10 + (xi[cc] - rsx2);
          wB[r * 3 + cc] = yw[r] * xw[cc];
        }
    } else {
      int xi[3]; float xw[3]; axis3(x0, x1, wx, 1, 128, xi, xw);
      int yi[3]; float yw[3]; axis3(y0, y1, wy, 1, 128, yi, yw);
#pragma unroll
      for (int r = 0; r < 3; r++)
#pragma unroll
        for (int cc = 0; cc < 3; cc++) {
          goB[r * 3 + cc] = yi[r] * 128 + xi[cc];
          wB[r * 3 + cc] = yw[r] * xw[cc];
        }
    }
    const float* p1n = pyr1 + ((size_t)(n * C + gb)) * (128 * 128);
    const float* inA = inputs + ((size_t)(n * C + gb)) * HW;
#pragma unroll 1
    for (int c = 0; c < 32; c++) {
      float a;
      if (l0 == 1) {
        const float* pc = p1n + (size_t)c * (128 * 128);
        a = 0.f;
#pragma unroll
        for (int t = 0; t < 9; t++) a = fmaf(wAg[t], pc[goA[t]], a);
      } else {
        const float* ip = inA + (size_t)c * HW;
        float v00 = ip[y0 * W + x0], v01 = ip[y0 * W + x1];
        float v10 = ip[y1 * W + x0], v11 = ip[y1 * W + x1];
        a = (v00 * (1.f - wx) + v01 * wx) * (1.f - wy) +
            (v10 * (1.f - wx) + v11 * wx) * wy;
      }
      float b = 0.f;
      if (lB == 2) {
        const float* pB = lds + (c >> 2) * 400 + (c & 3);
#pragma unroll
        for (int t = 0; t < 9; t++) b = fmaf(wB[t], pB[tfB[t] * 4], b);
      } else {
        const float* pc = p1n + (size_t)c * (128 * 128);
#pragma unroll
        for (int t = 0; t < 9; t++) b = fmaf(wB[t], pc[goB[t]], b);
      }
      po[(size_t)c * HW] = fmaf(wl, b - a, a);
    }
  }
}

}  // namespace

extern "C" void kernel_launch(void* const* d_in, const int* in_sizes, int n_in,
                              void* d_out, int out_size, void* d_ws, size_t ws_size,
                              hipStream_t stream) {
  const float* inputs = (const float*)d_in[0];
  const float* grid = (const float*)d_in[1];
  float* out = (float*)d_out;
  float* ws = (float*)d_ws;

  float* pyr1 = ws;                                  // N*C*128*128 = 25.2 MB
  float* pyr2 = pyr1 + (size_t)N * C * 128 * 128;    // N*C*64*64   =  6.3 MB
  float* pyr3 = pyr2 + (size_t)N * C * 64 * 64;      // N*C*32*32   =  1.6 MB

  int NC = N * C;
  downsample1<<<dim3(16, NC), 256, 0, stream>>>(inputs, pyr1);
  downsample23<<<dim3(4, NC), 256, 0, stream>>>(pyr1, pyr2, pyr3);
  gather_tiled<<<dim3(256, 3, N), 256, 0, stream>>>(inputs, grid,
                                                    pyr1, pyr2, pyr3, out);
}